// Round 2
// baseline (80.698 us; speedup 1.0000x reference)
//
#include <hip/hip_runtime.h>

#define B 32
#define V 256
#define F 128
#define P 64
#define VT 8   // v-tile per block (main kernel)

#define LOG2E 1.44269504088896340736f

// ---------------------------------------------------------------------------
// Kernel 1: softmax over the B*F = 4096 logit rows (length P = 64).
// One wave per row; shuffle-tree max/sum (accurate: restores round-0 absmax).
// Writes normalized amplitudes to workspace (1 MB of the 256 MB ws).
// ---------------------------------------------------------------------------
__global__ __launch_bounds__(256) void softmax_kernel(
    const float* __restrict__ logits,  // (B, 1, F, P)
    float* __restrict__ amp_ws)        // (B*F, P)
{
    const int row  = blockIdx.x * 4 + (threadIdx.x >> 6);  // = b*F + f
    const int lane = threadIdx.x & 63;
    const int idx  = row * P + lane;

    float l = logits[idx];
    float m = l;
    #pragma unroll
    for (int off = 32; off > 0; off >>= 1)
        m = fmaxf(m, __shfl_xor(m, off, 64));
    float e = __builtin_amdgcn_exp2f((l - m) * LOG2E);
    float s = e;
    #pragma unroll
    for (int off = 32; off > 0; off >>= 1)
        s += __shfl_xor(s, off, 64);
    amp_ws[idx] = e / s;
}

// ---------------------------------------------------------------------------
// Kernel 2: main evaluation. Grid B*(V/VT) = 1024 blocks x 256 threads.
// tid = vh*128 + f. Thread (f, vh) produces out[b, v0+2k+vh, f], k = 0..3.
// amp row lives in 64 VGPRs (loaded from ws), q2[b,:]*scl in 64 SGPRs.
// Inner element: v_sub(sgpr) + v_mul(neg mod) + v_exp + v_fmac
//   = 3 VALU (6 cy) + 1 trans (8 cy)  ->  trans-pipe bound.
// No LDS, no barriers; stores coalesced in f (256 B per wave).
// ---------------------------------------------------------------------------
__global__ __launch_bounds__(256) void extraction_kernel(
    const float* __restrict__ q2,      // (B, P)
    const float* __restrict__ amp_ws,  // (B*F, P) precomputed softmax
    const float* __restrict__ vol,     // (V, 1)
    const float* __restrict__ filt,    // (1, F)
    const float* __restrict__ sigma_p, // (1,)
    float* __restrict__ out)           // (B, V, F)
{
    const int bid = blockIdx.x;
    const int b   = bid >> 5;            // / (V/VT)
    const int v0  = (bid & 31) * VT;
    const int tid = threadIdx.x;
    const int f   = tid & (F - 1);
    const int vh  = tid >> 7;            // 0 or 1 (wave-uniform)

    const float sig = sigma_p[0];
    const float inv = 1.0f / (sig + 0.001f);
    // exp(-0.5*(d*inv)^2) = 2^(-(scl*d)^2), scl = sqrt(0.5*log2 e)*inv.
    // Pre-scale q and x separately: t = q*scl - x*scl. Absolute rounding in t
    // is ~2 ulp of |q*scl| <= ~160 -> ~4e-5 -> output error ~3e-5, safe.
    // (This is NOT the square-expansion that cancels ~6e4 terms — still the
    // factored (q - x) form.)
    const float scl = sqrtf(0.5f * LOG2E) * inv;

    // ---- amp[b,f,:] -> 64 VGPRs (16x global_load_dwordx4, L2-hot) ----
    float amp[P];
    const float4* a4 = (const float4*)(amp_ws + (b * F + f) * P);
    #pragma unroll
    for (int j = 0; j < P / 4; ++j) {
        float4 t = a4[j];
        amp[4 * j + 0] = t.x;
        amp[4 * j + 1] = t.y;
        amp[4 * j + 2] = t.z;
        amp[4 * j + 3] = t.w;
    }

    // ---- q2[b,:]*scl pinned wave-uniform (SGPRs) ----
    float qs[P];
    #pragma unroll
    for (int p = 0; p < P; ++p)
        qs[p] = __uint_as_float(__builtin_amdgcn_readfirstlane(
                    __float_as_uint(q2[b * P + p] * scl)));

    const float ffs = filt[f] * scl;

    #pragma unroll 1
    for (int k = 0; k < VT / 2; ++k) {
        const int v = v0 + 2 * k + vh;
        const float x = vol[v] * ffs;    // vol[v] wave-uniform broadcast load
        float a0 = 0.f, a1 = 0.f, a2 = 0.f, a3 = 0.f;
        #pragma unroll
        for (int p = 0; p < P; p += 4) {
            float t0 = qs[p + 0] - x;
            float t1 = qs[p + 1] - x;
            float t2 = qs[p + 2] - x;
            float t3 = qs[p + 3] - x;
            a0 += amp[p + 0] * __builtin_amdgcn_exp2f(-(t0 * t0));
            a1 += amp[p + 1] * __builtin_amdgcn_exp2f(-(t1 * t1));
            a2 += amp[p + 2] * __builtin_amdgcn_exp2f(-(t2 * t2));
            a3 += amp[p + 3] * __builtin_amdgcn_exp2f(-(t3 * t3));
        }
        out[(b * V + v) * F + f] = (a0 + a1) + (a2 + a3);  // coalesced in f
    }
}

extern "C" void kernel_launch(void* const* d_in, const int* in_sizes, int n_in,
                              void* d_out, int out_size, void* d_ws, size_t ws_size,
                              hipStream_t stream) {
    const float* q2     = (const float*)d_in[0]; // (32, 64)
    const float* logits = (const float*)d_in[1]; // (32, 1, 128, 64)
    const float* vol    = (const float*)d_in[2]; // (256, 1)
    const float* filt   = (const float*)d_in[3]; // (1, 128)
    const float* sigma  = (const float*)d_in[4]; // scalar
    float* out = (float*)d_out;                  // (32, 256, 128)
    float* amp_ws = (float*)d_ws;                // needs B*F*P*4 = 1 MB of ws

    softmax_kernel<<<B * F / 4, 256, 0, stream>>>(logits, amp_ws);
    extraction_kernel<<<B * (V / VT), 256, 0, stream>>>(q2, amp_ws, vol, filt, sigma, out);
}

// Round 3
// 75.987 us; speedup vs baseline: 1.0620x; 1.0620x over previous
//
#include <hip/hip_runtime.h>

#define B 32
#define V 256
#define F 128
#define P 64

#define LOG2E 1.44269504088896340736f

// One block per (b, f) pair: 4096 blocks x 256 threads (thread = v).
// Wave 0 does the 64-wide softmax (P == wavefront size) into LDS, then all
// 256 threads run the P-loop with LDS broadcast reads of (q, amp).
//
// SESSION NOTE (rounds 0-2): this structure, a pure-register/SGPR variant,
// and a two-dispatch split-softmax variant all measure 76-81 us. The timed
// iteration is dominated by the harness's 268 MB workspace poison fill
// (41 us @ 82% HBM peak) + ~8 fixed dispatches; the kernel itself is ~5 us
// (1.05M wave-exp / 1024 SIMDs x 8 cy = 3.4 us trans floor, VALU co-issued).
// Keep: single dispatch (each extra dispatch costs ~2 us), wave-tree softmax
// (serial per-thread sum degraded absmax 1.2e-4 -> 9.8e-4).
__global__ __launch_bounds__(256) void extraction_kernel(
    const float* __restrict__ q2,      // (B, P)
    const float* __restrict__ logits,  // (B, 1, F, P)
    const float* __restrict__ vol,     // (V, 1)
    const float* __restrict__ filt,    // (1, F)
    const float* __restrict__ sigma_p, // (1,)
    float* __restrict__ out)           // (B, V, F)
{
    const int bid = blockIdx.x;        // = b * F + f
    const int b   = bid >> 7;          // / F
    const int f   = bid & (F - 1);
    const int tid = threadIdx.x;       // = v

    __shared__ float q_s[P];
    __shared__ float amp_s[P];

    // Prologue: threads 0..63 (exactly one wave) compute softmax of
    // logits[b, 0, f, :] and stage q2[b, :].
    if (tid < P) {
        float l = logits[bid * P + tid];
        float m = l;
        #pragma unroll
        for (int off = 32; off > 0; off >>= 1)
            m = fmaxf(m, __shfl_xor(m, off, 64));
        float e = __builtin_amdgcn_exp2f((l - m) * LOG2E);
        float s = e;
        #pragma unroll
        for (int off = 32; off > 0; off >>= 1)
            s += __shfl_xor(s, off, 64);
        amp_s[tid] = e / s;
        q_s[tid]   = q2[b * P + tid];
    }
    __syncthreads();

    const float sig = sigma_p[0];                 // wave-uniform scalar
    const float inv = 1.0f / (sig + 0.001f);
    const float kk  = -0.5f * LOG2E * inv * inv;  // exp(-0.5 (d*inv)^2) = 2^(kk*d^2)

    const float x = vol[tid] * filt[f];           // filt[f] wave-uniform

    // NOTE: keep arg = kk*(x-q)^2 in the factored form. Expanding into
    // kx^2 - 2kxq + kq^2 loses ~0.01-0.02 absolute in the exponent at
    // |terms| ~ 6e4 (fp32 ulp) -> ~1% term error, over threshold.
    float acc0 = 0.f, acc1 = 0.f, acc2 = 0.f, acc3 = 0.f;
    const float4* q4 = (const float4*)q_s;
    const float4* a4 = (const float4*)amp_s;
    #pragma unroll
    for (int j = 0; j < P / 4; ++j) {
        float4 qv = q4[j];   // ds_read_b128, same-address broadcast
        float4 av = a4[j];
        float d0 = x - qv.x;
        float d1 = x - qv.y;
        float d2 = x - qv.z;
        float d3 = x - qv.w;
        acc0 += av.x * __builtin_amdgcn_exp2f(kk * d0 * d0);
        acc1 += av.y * __builtin_amdgcn_exp2f(kk * d1 * d1);
        acc2 += av.z * __builtin_amdgcn_exp2f(kk * d2 * d2);
        acc3 += av.w * __builtin_amdgcn_exp2f(kk * d3 * d3);
    }

    out[(b * V + tid) * F + f] = (acc0 + acc1) + (acc2 + acc3);
}

extern "C" void kernel_launch(void* const* d_in, const int* in_sizes, int n_in,
                              void* d_out, int out_size, void* d_ws, size_t ws_size,
                              hipStream_t stream) {
    const float* q2     = (const float*)d_in[0]; // (32, 64)
    const float* logits = (const float*)d_in[1]; // (32, 1, 128, 64)
    const float* vol    = (const float*)d_in[2]; // (256, 1)
    const float* filt   = (const float*)d_in[3]; // (1, 128)
    const float* sigma  = (const float*)d_in[4]; // scalar
    float* out = (float*)d_out;                  // (32, 256, 128)

    extraction_kernel<<<B * F, V, 0, stream>>>(q2, logits, vol, filt, sigma, out);
}